// Round 10
// baseline (282.495 us; speedup 1.0000x reference)
//
#include <hip/hip_runtime.h>

// RelationAwareDiscriminator:
//   out[b,u,v] = sigmoid( sum_{d,e} UE[u,d] * R[r[b],d,e] * VE[v,e] )
// Dedup: out[b] depends on b only via r[b] (64 distinct relations).
// R10: contiguous-store slab design. Evidence: R5's plain copy hit 6.7 TB/s
// combined with 128KB-contiguous streams; all 64-wide-tile variants stall
// at ~4-5 TB/s (256B chunks @ 2KB stride -> DRAM row thrash). Each block
// now owns a 16-row x 512-col slab; replica stores are 8KB-contiguous per
// wave (32KB per block per match), register-hoisted, issued back-to-back.

#define BATCH 512
#define DIM   128
#define NRELS 64
#define NTHR  256
#define UROWS 16
#define SROW  (BATCH + 4)   // S row stride (floats); keeps float4 alignment

typedef float floatx2 __attribute__((ext_vector_type(2)));
typedef float floatx4 __attribute__((ext_vector_type(4)));

// LDS-only barrier: orders ds ops without draining global stores
// (__syncthreads emits s_waitcnt vmcnt(0), serializing the store stream).
__device__ __forceinline__ void lds_barrier() {
    asm volatile("s_waitcnt lgkmcnt(0)" ::: "memory");
    __builtin_amdgcn_s_barrier();
    __builtin_amdgcn_sched_barrier(0);
}

__global__ __launch_bounds__(NTHR, 2)
void rad_slab_kernel(const int* __restrict__ u_idx,
                     const int* __restrict__ v_idx,
                     const int* __restrict__ r_idx,
                     const float* __restrict__ nodes,   // [100000][128]
                     const float* __restrict__ rels,    // [64][128][128]
                     float* __restrict__ out)           // [512][512][512]
{
    // 2048 blocks. XCD-colocating decode (assume XCD = bid%8):
    //   x = bid&7, k = bid>>3, rel = k>>2, uslab = (k&3)*8 + x.
    // Same-rel blocks are consecutive on one XCD -> R + v reads L2-shared;
    // every XCD gets every rel (4 slabs each) -> store bytes balanced.
    const int bid = (int)blockIdx.x;
    const int x   = bid & 7;
    const int k   = bid >> 3;
    const int rel = k >> 2;
    const int ut0 = (((k & 3) << 3) | x) << 4;   // 0,16,...,496

    __shared__ int s_match[BATCH];
    __shared__ int s_mc;
    __shared__ __align__(16) float TsT[DIM * UROWS];      // [e][r]  8 KB
    __shared__ __align__(16) float S[UROWS * SROW];       // slab   33 KB
    __shared__ __align__(16) float buf[DIM * 64];         // 32 KB: A: UEsT(8K)+Rs(8K); B: VEsT(32K)

    const int t  = (int)threadIdx.x;
    const int r  = t >> 4;    // 0..15: u-row within slab
    const int tx = t & 15;

    if (t == 0) s_mc = 0;
    __syncthreads();
    for (int i = t; i < BATCH; i += NTHR) {
        if (r_idx[i] == rel) {
            int p = atomicAdd(&s_mc, 1);
            s_match[p] = i;
        }
    }

    float* UEsT = buf;                 // [d][r] 128x16, 8 KB
    float* Rs   = buf + DIM * UROWS;   // [dd][e] 16x128, 8 KB

    // Gather 16 u-rows transposed [d][r].
    for (int i = t; i < UROWS * (DIM / 4); i += NTHR) {   // 512: 2 iters
        const int row = i & 15;
        const int dc  = i >> 4;   // 0..31
        const float4 val = *reinterpret_cast<const float4*>(
            nodes + (size_t)u_idx[ut0 + row] * DIM + dc * 4);
        UEsT[(dc * 4 + 0) * UROWS + row] = val.x;
        UEsT[(dc * 4 + 1) * UROWS + row] = val.y;
        UEsT[(dc * 4 + 2) * UROWS + row] = val.z;
        UEsT[(dc * 4 + 3) * UROWS + row] = val.w;
    }
    __syncthreads();
    const int mc = s_mc;
    if (mc == 0) return;

    // ---------------- Phase A: T[e][r] = sum_d UE[r][d] * R[d][e]
    float accA[8];
    #pragma unroll
    for (int j = 0; j < 8; ++j) accA[j] = 0.f;

    const float* Rbase = rels + (size_t)rel * DIM * DIM;
    for (int dch = 0; dch < DIM / 16; ++dch) {
        for (int i = t; i < 16 * (DIM / 4); i += NTHR) {  // 512: 2 iters
            const int rr = i >> 5;
            const int cc = i & 31;
            *reinterpret_cast<float4*>(Rs + rr * DIM + cc * 4) =
                *reinterpret_cast<const float4*>(
                    Rbase + (size_t)(dch * 16 + rr) * DIM + cc * 4);
        }
        lds_barrier();
        #pragma unroll
        for (int dd = 0; dd < 16; ++dd) {
            const int d = dch * 16 + dd;
            const float a  = UEsT[d * UROWS + r];
            const float4 b0 = *reinterpret_cast<const float4*>(Rs + dd * DIM + tx * 4);
            const float4 b1 = *reinterpret_cast<const float4*>(Rs + dd * DIM + 64 + tx * 4);
            accA[0] = fmaf(a, b0.x, accA[0]);
            accA[1] = fmaf(a, b0.y, accA[1]);
            accA[2] = fmaf(a, b0.z, accA[2]);
            accA[3] = fmaf(a, b0.w, accA[3]);
            accA[4] = fmaf(a, b1.x, accA[4]);
            accA[5] = fmaf(a, b1.y, accA[5]);
            accA[6] = fmaf(a, b1.z, accA[6]);
            accA[7] = fmaf(a, b1.w, accA[7]);
        }
        lds_barrier();
    }
    // Dump T (written and later read by the same row-group wave).
    #pragma unroll
    for (int j = 0; j < 8; ++j) {
        const int e = tx * 4 + (j & 3) + 64 * (j >> 2);
        TsT[e * UROWS + r] = accA[j];
    }

    // ---------------- Phase B: slab accumulate, col-chunks of 64 v
    float* VEsT = buf;   // [e][v] 128x64, 32 KB (overwrites UEsT/Rs)
    for (int vt = 0; vt < BATCH / 64; ++vt) {
        lds_barrier();   // prev chunk's VEsT reads done (1st: phase A done)
        for (int i = t; i < 64 * (DIM / 4); i += NTHR) {  // 2048: 8 iters
            const int row = i & 63;
            const int ec  = i >> 6;
            const float4 val = *reinterpret_cast<const float4*>(
                nodes + (size_t)v_idx[vt * 64 + row] * DIM + ec * 4);
            VEsT[(ec * 4 + 0) * 64 + row] = val.x;
            VEsT[(ec * 4 + 1) * 64 + row] = val.y;
            VEsT[(ec * 4 + 2) * 64 + row] = val.z;
            VEsT[(ec * 4 + 3) * 64 + row] = val.w;
        }
        lds_barrier();

        float a0 = 0.f, a1 = 0.f, a2 = 0.f, a3 = 0.f;
        #pragma unroll 8
        for (int e = 0; e < DIM; ++e) {
            const float  a = TsT[e * UROWS + r];
            const float4 b = *reinterpret_cast<const float4*>(VEsT + e * 64 + tx * 4);
            a0 = fmaf(a, b.x, a0);
            a1 = fmaf(a, b.y, a1);
            a2 = fmaf(a, b.z, a2);
            a3 = fmaf(a, b.w, a3);
        }
        float4 sg;
        sg.x = 1.f / (1.f + __expf(-a0));
        sg.y = 1.f / (1.f + __expf(-a1));
        sg.z = 1.f / (1.f + __expf(-a2));
        sg.w = 1.f / (1.f + __expf(-a3));
        // S row r written only by threads of the owning wave (r = 4w..4w+3).
        *reinterpret_cast<float4*>(S + r * SROW + vt * 64 + tx * 4) = sg;
    }

    // ---------------- Store phase: hoist this wave's 4 rows to registers,
    // then write each replica as contiguous 2KB rows (8KB span per wave).
    const int w = t >> 6;     // wave 0..3 owns rows 4w..4w+3
    const int l = t & 63;
    floatx2 rv[4][4];
    #pragma unroll
    for (int rr = 0; rr < 4; ++rr)
        #pragma unroll
        for (int c = 0; c < 4; ++c)
            rv[rr][c] = *reinterpret_cast<const floatx2*>(
                S + (w * 4 + rr) * SROW + c * 128 + 2 * l);
    // (intra-wave LDS dependency: compiler inserts lgkmcnt waits)

    for (int m = 0; m < mc; ++m) {
        const int bb = s_match[m];
        float* ob = out + ((size_t)bb << 18) + ((size_t)ut0 << 9);
        #pragma unroll
        for (int rr = 0; rr < 4; ++rr) {
            float* orow = ob + ((size_t)(w * 4 + rr) << 9) + 2 * l;
            #pragma unroll
            for (int c = 0; c < 4; ++c)
                *reinterpret_cast<floatx2*>(orow + c * 128) = rv[rr][c];
        }
    }
}

extern "C" void kernel_launch(void* const* d_in, const int* in_sizes, int n_in,
                              void* d_out, int out_size, void* d_ws, size_t ws_size,
                              hipStream_t stream) {
    const int*   u_idx = (const int*)d_in[0];
    const int*   v_idx = (const int*)d_in[1];
    const int*   r_idx = (const int*)d_in[2];
    const float* nodes = (const float*)d_in[3];
    const float* rels  = (const float*)d_in[4];
    float* out = (float*)d_out;

    dim3 grid(NRELS * 32); // 2048 blocks: 64 rels x 32 u-slabs of 16 rows
    dim3 block(NTHR);
    rad_slab_kernel<<<grid, block, 0, stream>>>(u_idx, v_idx, r_idx, nodes, rels, out);
}

// Round 11
// 152.878 us; speedup vs baseline: 1.8478x; 1.8478x over previous
//
#include <hip/hip_runtime.h>

// RelationAwareDiscriminator:
//   out[b,u,v] = sigmoid( sum_{d,e} UE[u,d] * R[r[b],d,e] * VE[v,e] )
// Dedup: out[b] depends on b only via r[b] (64 distinct relations).
// R11: R7 structure with 256-col-wide phase-B tiles so every wave store
// instruction is 1KB CONTIGUOUS (64 lanes x float4). Evidence: R5's copy
// (1KB/instr) ran 6.7 TB/s; all 64-wide-tile variants (256B/instr @ 2KB
// stride) deliver ~3.8-4.5 TB/s. 64 acc/thread keeps compute VALU-bound
// (5 b128 per 64 FMAs), fixing R10's LDS-bound regression.

#define BATCH 512
#define DIM   128
#define NRELS 64
#define NTHR  256

typedef float floatx4 __attribute__((ext_vector_type(4)));

// LDS-only barrier: orders ds ops without draining global stores
// (__syncthreads emits s_waitcnt vmcnt(0), serializing the store stream).
__device__ __forceinline__ void lds_barrier() {
    asm volatile("s_waitcnt lgkmcnt(0)" ::: "memory");
    __builtin_amdgcn_s_barrier();
    __builtin_amdgcn_sched_barrier(0);
}

__global__ __launch_bounds__(NTHR, 2)
void rad_wide_kernel(const int* __restrict__ u_idx,
                     const int* __restrict__ v_idx,
                     const int* __restrict__ r_idx,
                     const float* __restrict__ nodes,   // [100000][128]
                     const float* __restrict__ rels,    // [64][128][128]
                     float* __restrict__ out)           // [512][512][512]
{
    // XCD-colocating swizzle (same as R7): 8 ut-siblings of a rel share an
    // XCD -> R and v/u rows served from that XCD's L2.
    const int bid = (int)blockIdx.x;
    const int rel = ((bid & 7) << 3) | (bid >> 6);
    const int ut0 = ((bid >> 3) & 7) * 64;

    __shared__ int s_match[BATCH];
    __shared__ int s_mc;
    __shared__ __align__(16) float TsT[DIM * 64];              // [e][u], 32 KB
    __shared__ __align__(16) float buf[DIM * 64 + 16 * DIM];   // 40 KB scratch

    const int t  = (int)threadIdx.x;
    const int tu = t >> 4;   // phase A: 0..15 (u group of 4)
    const int tx = t & 15;   // phase A: 0..15 (e group)

    if (t == 0) s_mc = 0;
    __syncthreads();
    for (int i = t; i < BATCH; i += NTHR) {
        if (r_idx[i] == rel) {
            int p = atomicAdd(&s_mc, 1);
            s_match[p] = i;
        }
    }

    float* UEsT = buf;               // [d][u] 128x64, 32 KB (phase A)
    float* Rs   = buf + DIM * 64;    // [dd][e] 16x128, 8 KB (phase A)

    // Gather u-embedding rows, store transposed [d][u].
    for (int i = t; i < 64 * (DIM / 4); i += NTHR) {
        const int row = i & 63;
        const int dc  = i >> 6; // 0..31
        const float4 val = *reinterpret_cast<const float4*>(
            nodes + (size_t)u_idx[ut0 + row] * DIM + dc * 4);
        UEsT[(dc * 4 + 0) * 64 + row] = val.x;
        UEsT[(dc * 4 + 1) * 64 + row] = val.y;
        UEsT[(dc * 4 + 2) * 64 + row] = val.z;
        UEsT[(dc * 4 + 3) * 64 + row] = val.w;
    }
    __syncthreads();
    const int mc = s_mc;
    if (mc == 0) return;

    // ---------------- Phase A (verbatim R7): TsT[e][u] = UE.R
    float accA[4][8];
    #pragma unroll
    for (int i = 0; i < 4; ++i)
        #pragma unroll
        for (int j = 0; j < 8; ++j) accA[i][j] = 0.f;

    const float* Rbase = rels + (size_t)rel * DIM * DIM;
    for (int dch = 0; dch < DIM / 16; ++dch) {
        for (int i = t; i < 16 * (DIM / 4); i += NTHR) {
            const int rr = i >> 5;
            const int cc = i & 31;
            *reinterpret_cast<float4*>(Rs + rr * DIM + cc * 4) =
                *reinterpret_cast<const float4*>(
                    Rbase + (size_t)(dch * 16 + rr) * DIM + cc * 4);
        }
        lds_barrier();
        #pragma unroll
        for (int dd = 0; dd < 16; ++dd) {
            const int d = dch * 16 + dd;
            const float4 a  = *reinterpret_cast<const float4*>(UEsT + d * 64 + tu * 4);
            const float4 b0 = *reinterpret_cast<const float4*>(Rs + dd * DIM + tx * 4);
            const float4 b1 = *reinterpret_cast<const float4*>(Rs + dd * DIM + 64 + tx * 4);
            const float av[4] = {a.x, a.y, a.z, a.w};
            const float bv[8] = {b0.x, b0.y, b0.z, b0.w, b1.x, b1.y, b1.z, b1.w};
            #pragma unroll
            for (int i = 0; i < 4; ++i)
                #pragma unroll
                for (int j = 0; j < 8; ++j)
                    accA[i][j] = fmaf(av[i], bv[j], accA[i][j]);
        }
        lds_barrier();
    }

    #pragma unroll
    for (int j = 0; j < 8; ++j) {
        const int e = (j < 4) ? (tx * 4 + j) : (64 + tx * 4 + (j - 4));
        #pragma unroll
        for (int i = 0; i < 4; ++i)
            TsT[e * 64 + tu * 4 + i] = accA[i][j];
    }

    // ---------------- Phase B: two 256-col halves, 64x256 tile in regs.
    // Thread layout: wave w = t>>6 owns rows rt = w*16 .. +15;
    // lane l = t&63 owns cols ct = l*4 .. +3 (of the 256-wide half).
    const int w  = t >> 6;
    const int rt = w * 16;
    const int ct = (t & 63) * 4;
    float* VEs = buf;   // [16][256] 16 KB, reuses phase-A scratch

    for (int vh = 0; vh < 2; ++vh) {
        float acc[16][4];
        #pragma unroll
        for (int r = 0; r < 16; ++r)
            #pragma unroll
            for (int c = 0; c < 4; ++c) acc[r][c] = 0.f;

        for (int ec = 0; ec < 8; ++ec) {
            lds_barrier();   // prior VEs readers done (also orders TsT writes)
            // Stage VEs[ee][v] = VE[vh*256+v][ec*16+ee]; 1024 float4 loads.
            #pragma unroll
            for (int k = 0; k < 4; ++k) {
                const int i  = t + k * NTHR;
                const int v  = i & 255;
                const int c4 = i >> 8;          // 0..3
                const float4 val = *reinterpret_cast<const float4*>(
                    nodes + (size_t)v_idx[vh * 256 + v] * DIM + ec * 16 + c4 * 4);
                VEs[(c4 * 4 + 0) * 256 + v] = val.x;
                VEs[(c4 * 4 + 1) * 256 + v] = val.y;
                VEs[(c4 * 4 + 2) * 256 + v] = val.z;
                VEs[(c4 * 4 + 3) * 256 + v] = val.w;
            }
            lds_barrier();

            #pragma unroll 2
            for (int ee = 0; ee < 16; ++ee) {
                const int e = ec * 16 + ee;
                // T rows rt..rt+15 (wave-uniform: LDS broadcast, free)
                const float4 t0 = *reinterpret_cast<const float4*>(TsT + e * 64 + rt);
                const float4 t1 = *reinterpret_cast<const float4*>(TsT + e * 64 + rt + 4);
                const float4 t2 = *reinterpret_cast<const float4*>(TsT + e * 64 + rt + 8);
                const float4 t3 = *reinterpret_cast<const float4*>(TsT + e * 64 + rt + 12);
                const float4 bv = *reinterpret_cast<const float4*>(VEs + ee * 256 + ct);
                const float tr[16] = {t0.x, t0.y, t0.z, t0.w,
                                      t1.x, t1.y, t1.z, t1.w,
                                      t2.x, t2.y, t2.z, t2.w,
                                      t3.x, t3.y, t3.z, t3.w};
                const float bc[4] = {bv.x, bv.y, bv.z, bv.w};
                #pragma unroll
                for (int r = 0; r < 16; ++r)
                    #pragma unroll
                    for (int c = 0; c < 4; ++c)
                        acc[r][c] = fmaf(tr[r], bc[c], acc[r][c]);
            }
        }

        // Sigmoid into vector regs.
        floatx4 sg[16];
        #pragma unroll
        for (int r = 0; r < 16; ++r) {
            sg[r].x = 1.f / (1.f + __expf(-acc[r][0]));
            sg[r].y = 1.f / (1.f + __expf(-acc[r][1]));
            sg[r].z = 1.f / (1.f + __expf(-acc[r][2]));
            sg[r].w = 1.f / (1.f + __expf(-acc[r][3]));
        }

        // Replicate: per (m,r) ONE wave-instruction = 64 lanes x 16B = 1KB
        // CONTIGUOUS. m outer -> each wave writes 16 consecutive rows of a
        // plane back-to-back (128KB locality region per replica).
        for (int m = 0; m < mc; ++m) {
            const int bb = s_match[m];
            float* obase = out + ((size_t)bb << 18)
                               + ((size_t)(ut0 + rt) << 9) + vh * 256 + ct;
            #pragma unroll
            for (int r = 0; r < 16; ++r) {
                __builtin_nontemporal_store(
                    sg[r], reinterpret_cast<floatx4*>(obase + ((size_t)r << 9)));
            }
        }
    }
}

extern "C" void kernel_launch(void* const* d_in, const int* in_sizes, int n_in,
                              void* d_out, int out_size, void* d_ws, size_t ws_size,
                              hipStream_t stream) {
    const int*   u_idx = (const int*)d_in[0];
    const int*   v_idx = (const int*)d_in[1];
    const int*   r_idx = (const int*)d_in[2];
    const float* nodes = (const float*)d_in[3];
    const float* rels  = (const float*)d_in[4];
    float* out = (float*)d_out;

    dim3 grid(NRELS * 8); // 512 blocks, XCD-swizzled inside the kernel
    dim3 block(NTHR);
    rad_wide_kernel<<<grid, block, 0, stream>>>(u_idx, v_idx, r_idx, nodes, rels, out);
}